// Round 14
// baseline (284.178 us; speedup 1.0000x reference)
//
#include <hip/hip_runtime.h>
#include <math.h>

#define IMH 480
#define IMW 640
#define HW (IMH*IMW)
#define KPT 512
#define DESC 256
#define CAP 12288
#define NMSR 3

// ---------------------------------------------------------------- BAD offsets at COMPILE TIME
// np.random.RandomState(42).uniform(-8,8,(256,4)) -> np.round (half-to-even) -> int.
struct OffsTable { int v[1024]; };

constexpr unsigned mt_temper(unsigned y) {
  y ^= (y >> 11);
  y ^= (y << 7)  & 0x9d2c5680u;
  y ^= (y << 15) & 0xefc60000u;
  y ^= (y >> 18);
  return y;
}

constexpr OffsTable make_offs() {
  OffsTable T{};
  unsigned mt[624]{};
  unsigned s = 42u;
  for (int i = 0; i < 624; ++i) { mt[i] = s; s = 1812433253u * (s ^ (s >> 30)) + (unsigned)i + 1u; }
  int mti = 624;
  unsigned draws[2048]{};
  for (int i = 0; i < 2048; ++i) {
    if (mti >= 624) {
      for (int k = 0; k < 624; ++k) {
        unsigned y = (mt[k] & 0x80000000u) | (mt[(k + 1) % 624] & 0x7fffffffu);
        unsigned v = mt[(k + 397) % 624] ^ (y >> 1);
        if (y & 1u) v ^= 0x9908b0dfu;
        mt[k] = v;
      }
      mti = 0;
    }
    draws[i] = mt_temper(mt[mti++]);
  }
  for (int i = 0; i < 1024; ++i) {
    unsigned a = draws[2 * i] >> 5, b = draws[2 * i + 1] >> 6;
    double r = ((double)a * 67108864.0 + (double)b) / 9007199254740992.0;
    double val = -8.0 + 16.0 * r;
    double f = (double)(long long)val;
    if (val < f) f -= 1.0;                 // floor
    double diff = val - f;
    double rounded;
    if (diff > 0.5) rounded = f + 1.0;
    else if (diff < 0.5) rounded = f;
    else { long long fi = (long long)f; rounded = (fi % 2 == 0) ? f : f + 1.0; }  // half->even
    T.v[i] = (int)rounded;
  }
  return T;
}

__constant__ OffsTable OFFS_TAB = make_offs();

// ---------------------------------------------------------------- init
__global__ void init_misc_kernel(int* __restrict__ counts, float* __restrict__ sel_val,
                                 int* __restrict__ sel_idx, float* __restrict__ a,
                                 float* __restrict__ b, int* __restrict__ rank_arr,
                                 float* __restrict__ K, float* __restrict__ Kt) {
  int t = blockIdx.x * blockDim.x + threadIdx.x;
  if (t < 2) counts[t] = 0;
  if (t < 2 * KPT) { sel_val[t] = 0.f; sel_idx[t] = -1; }
  if (t < 513) { a[t] = 1.f; b[t] = 1.f; }   // b=exp(v)=1 initial; a overwritten first phase
  if (t < 513) {
    // dustbin row/col of the linear-domain kernel matrix: exp(UNUSED/EPS)=exp(1)
    float e = expf(1.0f);
    K[(size_t)KPT * 513 + t] = e;  K[(size_t)t * 513 + KPT] = e;
    Kt[(size_t)KPT * 513 + t] = e; Kt[(size_t)t * 513 + KPT] = e;
  }
  for (int i = t; i < 2 * CAP; i += 16384) rank_arr[i] = 0;
}

// ---------------------------------------------------------------- fused detector + NMS
// Interior blocks (full halo in-range) take a branch-free fast path — the
// staging ternary, -inf pad, and 9 per-center border tests are block-uniformly
// dead there (464 of 600 blocks/batch). FP sequence identical -> bit-identical.
#define FTW 64
#define FTH 8
__global__ void det_nms_kernel(const float* __restrict__ img0, const float* __restrict__ img1,
                               float* __restrict__ smooth,
                               float* __restrict__ cand_val, int* __restrict__ cand_idx,
                               int* __restrict__ counts) {
  const int b = blockIdx.z;
  const int x0 = blockIdx.x * FTW;
  const int y0 = blockIdx.y * FTH;
  const bool interior = (blockIdx.x >= 1) && (blockIdx.x <= 8) &&
                        (blockIdx.y >= 1) && (blockIdx.y <= 58);
  const float* __restrict__ img = b ? img1 : img0;
  __shared__ float im[(FTH + 10) * (FTW + 10)];   // 18 x 74 image stage (0 OOB)
  __shared__ float scs[(FTH + 6) * (FTW + 6)];    // 14 x 70 scores (-inf OOB)
  __shared__ float hm[(FTH + 6) * FTW];           // 14 x 64 horizontal 7-max
  __shared__ float lval[128];
  __shared__ int lidx[128];
  __shared__ int lcnt, gbase;
  const int tid = threadIdx.x;
  if (tid == 0) lcnt = 0;
  if (interior) {
    for (int i = tid; i < 18 * 74; i += 256) {
      int ly = i / 74, lx = i - ly * 74;
      im[i] = img[(y0 + ly - 5) * IMW + (x0 + lx - 5)];
    }
  } else {
    for (int i = tid; i < 18 * 74; i += 256) {
      int ly = i / 74, lx = i - ly * 74;
      int gy = y0 + ly - 5, gx = x0 + lx - 5;
      im[i] = (gy >= 0 && gy < IMH && gx >= 0 && gx < IMW) ? img[gy * IMW + gx] : 0.f;
    }
  }
  __syncthreads();
  if (interior) {
    for (int i = tid; i < 14 * 70; i += 256) {
      int ly = i / 70, lx = i - ly * 70;
      int gy = y0 + ly - 3, gx = x0 + lx - 3;
      float a[5][5];
      #pragma unroll
      for (int ii = 0; ii < 5; ++ii)
        #pragma unroll
        for (int jj = 0; jj < 5; ++jj)
          a[ii][jj] = im[(ly + ii) * 74 + lx + jj];
      float sm = 0.f;
      #pragma unroll
      for (int ii = 0; ii < 5; ++ii)
        #pragma unroll
        for (int jj = 0; jj < 5; ++jj) sm += a[ii][jj];
      if (ly >= 3 && ly < 3 + FTH && lx >= 3 && lx < 3 + FTW)
        smooth[b * HW + gy * IMW + gx] = sm * (1.f / 25.f);
      float sxx = 0.f, syy = 0.f, sxy = 0.f;
      #pragma unroll
      for (int cy = -1; cy <= 1; ++cy) {
        #pragma unroll
        for (int cx = -1; cx <= 1; ++cx) {
          int iu = cy + 2, iv = cx + 2;
          float ix = (a[iu - 1][iv + 1] - a[iu - 1][iv - 1])
                   + 2.f * (a[iu][iv + 1] - a[iu][iv - 1])
                   + (a[iu + 1][iv + 1] - a[iu + 1][iv - 1]);
          float iy = (a[iu + 1][iv - 1] + 2.f * a[iu + 1][iv] + a[iu + 1][iv + 1])
                   - (a[iu - 1][iv - 1] + 2.f * a[iu - 1][iv] + a[iu - 1][iv + 1]);
          sxx += ix * ix; syy += iy * iy; sxy += ix * iy;
        }
      }
      sxx *= (1.f / 9.f); syy *= (1.f / 9.f); sxy *= (1.f / 9.f);
      float half_tr = 0.5f * (sxx + syy);
      float hd = 0.5f * (sxx - syy);
      scs[i] = half_tr - sqrtf(hd * hd + sxy * sxy + 1e-12f);
    }
  } else {
    for (int i = tid; i < 14 * 70; i += 256) {
      int ly = i / 70, lx = i - ly * 70;
      int gy = y0 + ly - 3, gx = x0 + lx - 3;
      float sc;
      if (gy < 0 || gy >= IMH || gx < 0 || gx >= IMW) {
        sc = -INFINITY;                 // reference NMS pads with -inf
      } else {
        float a[5][5];
        #pragma unroll
        for (int ii = 0; ii < 5; ++ii)
          #pragma unroll
          for (int jj = 0; jj < 5; ++jj)
            a[ii][jj] = im[(ly + ii) * 74 + lx + jj];
        float sm = 0.f;
        #pragma unroll
        for (int ii = 0; ii < 5; ++ii)
          #pragma unroll
          for (int jj = 0; jj < 5; ++jj) sm += a[ii][jj];
        if (ly >= 3 && ly < 3 + FTH && lx >= 3 && lx < 3 + FTW)
          smooth[b * HW + gy * IMW + gx] = sm * (1.f / 25.f);
        float sxx = 0.f, syy = 0.f, sxy = 0.f;
        #pragma unroll
        for (int cy = -1; cy <= 1; ++cy) {
          #pragma unroll
          for (int cx = -1; cx <= 1; ++cx) {
            int yy = gy + cy, xx = gx + cx;
            if (yy < 0 || yy >= IMH || xx < 0 || xx >= IMW) continue;  // zero-pad box conv
            int iu = cy + 2, iv = cx + 2;
            float ix = (a[iu - 1][iv + 1] - a[iu - 1][iv - 1])
                     + 2.f * (a[iu][iv + 1] - a[iu][iv - 1])
                     + (a[iu + 1][iv + 1] - a[iu + 1][iv - 1]);
            float iy = (a[iu + 1][iv - 1] + 2.f * a[iu + 1][iv] + a[iu + 1][iv + 1])
                     - (a[iu - 1][iv - 1] + 2.f * a[iu - 1][iv] + a[iu - 1][iv + 1]);
            sxx += ix * ix; syy += iy * iy; sxy += ix * iy;
          }
        }
        sxx *= (1.f / 9.f); syy *= (1.f / 9.f); sxy *= (1.f / 9.f);
        float half_tr = 0.5f * (sxx + syy);
        float hd = 0.5f * (sxx - syy);
        sc = half_tr - sqrtf(hd * hd + sxy * sxy + 1e-12f);
      }
      scs[i] = sc;
    }
  }
  __syncthreads();
  for (int i = tid; i < 14 * 64; i += 256) {
    int ly = i / 64, lx = i - ly * 64;
    const float* r = scs + ly * 70 + lx;
    float m = r[0];
    #pragma unroll
    for (int d = 1; d < 7; ++d) m = fmaxf(m, r[d]);
    hm[i] = m;
  }
  __syncthreads();
  for (int i = tid; i < FTH * FTW; i += 256) {
    int ly = i >> 6, lx = i & 63;
    float s = scs[(ly + 3) * 70 + lx + 3];
    if (s > 0.f) {
      float m = hm[ly * 64 + lx];
      #pragma unroll
      for (int d = 1; d < 7; ++d) m = fmaxf(m, hm[(ly + d) * 64 + lx]);
      if (s >= m - 1e-7f) {
        int slot = atomicAdd(&lcnt, 1);
        if (slot < 128) { lval[slot] = s; lidx[slot] = (y0 + ly) * IMW + (x0 + lx); }
      }
    }
  }
  __syncthreads();
  if (tid == 0) gbase = atomicAdd(&counts[b], min(lcnt, 128));
  __syncthreads();
  int nc = min(lcnt, 128);
  for (int i = tid; i < nc; i += 256) {
    int slot = gbase + i;
    if (slot < CAP) {
      cand_val[b * CAP + slot] = lval[i];
      cand_idx[b * CAP + slot] = lidx[i];
    }
  }
}

// ---------------------------------------------------------------- top-512: 2D-tiled rank count
__global__ void rank_partial_kernel(const float* __restrict__ cand_val,
                                    const int* __restrict__ cand_idx,
                                    const int* __restrict__ counts,
                                    int* __restrict__ rank_arr) {
  int b = blockIdx.z;
  int n = counts[b]; if (n > CAP) n = CAP;
  if ((int)(blockIdx.x * 256) >= n || (int)(blockIdx.y * 256) >= n) return;
  const float* cv = cand_val + b * CAP;
  const int* ci = cand_idx + b * CAP;
  int i = blockIdx.x * 256 + threadIdx.x;
  int j = blockIdx.y * 256 + threadIdx.x;
  __shared__ unsigned long long sk[256];
  sk[threadIdx.x] = (j < n)
      ? (((unsigned long long)__float_as_uint(cv[j]) << 32) | (0xFFFFFFFFu - (unsigned)ci[j]))
      : 0ull;
  __syncthreads();
  if (i >= n) return;
  unsigned long long ki = ((unsigned long long)__float_as_uint(cv[i]) << 32)
                        | (0xFFFFFFFFu - (unsigned)ci[i]);
  int r = 0;
  #pragma unroll 8
  for (int t = 0; t < 256; ++t) r += (sk[t] > ki) ? 1 : 0;
  atomicAdd(&rank_arr[b * CAP + i], r);
}

__global__ void scatter_topk_kernel(const float* __restrict__ cand_val,
                                    const int* __restrict__ cand_idx,
                                    const int* __restrict__ counts,
                                    const int* __restrict__ rank_arr,
                                    float* __restrict__ sel_val, int* __restrict__ sel_idx) {
  int b = blockIdx.y;
  int n = counts[b]; if (n > CAP) n = CAP;
  int i = blockIdx.x * 256 + threadIdx.x;
  if (i >= n) return;
  int r = rank_arr[b * CAP + i];
  if (r < KPT) {
    sel_val[b * KPT + r] = cand_val[b * CAP + i];
    sel_idx[b * KPT + r] = cand_idx[b * CAP + i];
  }
}

// ---------------------------------------------------------------- kp out + BAD desc + L2 norm
__global__ void kp_desc_kernel(const float* __restrict__ sel_val, const int* __restrict__ sel_idx,
                               const float* __restrict__ smooth,
                               float* __restrict__ desc, float* __restrict__ a2_out,
                               float* __restrict__ out) {
  int blk = blockIdx.x;
  int b = blk >> 9;
  int k = blk & 511;
  int lane = threadIdx.x;
  float val = sel_val[b * KPT + k];
  int idx = sel_idx[b * KPT + k];
  bool valid = (val > 0.f) && (idx >= 0);
  int y = 0, x = 0;
  if (valid) { y = idx / IMW; x = idx - y * IMW; }
  const float* sm = smooth + b * HW;
  float d[4];
  #pragma unroll
  for (int t2 = 0; t2 < 4; ++t2) {
    int pp = (lane << 2) + t2;
    int oy1 = OFFS_TAB.v[4 * pp + 0], ox1 = OFFS_TAB.v[4 * pp + 1];
    int oy2 = OFFS_TAB.v[4 * pp + 2], ox2 = OFFS_TAB.v[4 * pp + 3];
    int ya = min(max(y + oy1, 0), IMH - 1), xa = min(max(x + ox1, 0), IMW - 1);
    int yb = min(max(y + oy2, 0), IMH - 1), xb = min(max(x + ox2, 0), IMW - 1);
    float v2 = sm[ya * IMW + xa] - sm[yb * IMW + xb];
    d[t2] = valid ? v2 : 0.f;
  }
  float ss = d[0] * d[0] + d[1] * d[1] + d[2] * d[2] + d[3] * d[3];
  #pragma unroll
  for (int off = 32; off; off >>= 1) ss += __shfl_down(ss, off);
  ss = __shfl(ss, 0);
  float scale = 1.f / (sqrtf(ss) + 1e-8f);
  float* dd = desc + (size_t)(b * KPT + k) * DESC;
  #pragma unroll
  for (int t2 = 0; t2 < 4; ++t2) dd[(lane << 2) + t2] = d[t2] * scale;
  if (lane == 0) {
    a2_out[b * KPT + k] = ss * scale * scale;
    float* kp = out + b * (2 * KPT) + k * 2;
    kp[0] = valid ? (float)y : -1.f;
    kp[1] = valid ? (float)x : -1.f;
  }
}

// ---------------------------------------------------------------- similarity: LDS-tiled GEMM, 512 blocks
#define CK 128
#define APITCH 34
#define BPITCH 18
__global__ __launch_bounds__(128) void similarity_tiled_kernel(
    const float* __restrict__ desc, const float* __restrict__ a2,
    float* __restrict__ K, float* __restrict__ Kt) {
  __shared__ float As[CK * APITCH];   // [k][row], 32 rows
  __shared__ float Bs[CK * BPITCH];   // [k][col], 16 cols
  __shared__ float T[32 * 17];        // output tile for coalesced writes
  const int tid = threadIdx.x;
  const int tx = tid & 7;         // col-pair index (16 cols)
  const int ty = tid >> 3;        // row-pair index (32 rows)
  const int row0 = blockIdx.y * 32;
  const int col0 = blockIdx.x * 16;
  float acc[2][2] = {};
  for (int kc = 0; kc < DESC; kc += CK) {
    for (int i = tid; i < 32 * CK; i += 128) {
      int c = i & (CK - 1), r = i >> 7;   // consecutive lanes -> consecutive c: coalesced
      As[c * APITCH + r] = desc[(size_t)(row0 + r) * DESC + kc + c];
    }
    for (int i = tid; i < 16 * CK; i += 128) {
      int c = i & (CK - 1), r = i >> 7;
      Bs[c * BPITCH + r] = desc[(size_t)(KPT + col0 + r) * DESC + kc + c];
    }
    __syncthreads();
    #pragma unroll 16
    for (int kk = 0; kk < CK; ++kk) {
      const float2 av = *(const float2*)&As[kk * APITCH + ty * 2];
      const float2 bv = *(const float2*)&Bs[kk * BPITCH + tx * 2];
      acc[0][0] += av.x * bv.x; acc[0][1] += av.x * bv.y;
      acc[1][0] += av.y * bv.x; acc[1][1] += av.y * bv.y;
    }
    __syncthreads();
  }
  float a2k[2], b2l[2];
  #pragma unroll
  for (int i = 0; i < 2; ++i) {
    a2k[i] = a2[row0 + ty * 2 + i];
    b2l[i] = a2[KPT + col0 + tx * 2 + i];
  }
  #pragma unroll
  for (int i = 0; i < 2; ++i)
    #pragma unroll
    for (int j = 0; j < 2; ++j) {
      float sq = fmaxf(a2k[i] + b2l[j] - 2.f * acc[i][j], 0.f);
      T[(ty * 2 + i) * 17 + tx * 2 + j] = expf(-sqrtf(sq + 1e-12f));
    }
  __syncthreads();
  for (int i = tid; i < 512; i += 128) {
    int r = i >> 4, c = i & 15;
    K[(size_t)(row0 + r) * 513 + col0 + c] = T[r * 17 + c];
  }
  for (int i = tid; i < 512; i += 128) {
    int r = i & 31, c = i >> 5;
    Kt[(size_t)(col0 + c) * 513 + row0 + r] = T[r * 17 + c];
  }
}

// ---------------------------------------------------------------- sinkhorn, linear domain, multi-dispatch
// a = mu / (K b);  b = nu / (K^T a);  probs = K * a * b * 1024.
// Dispatch boundary IS the grid barrier (~2 us, graph-amortized) — every
// hand-rolled cross-XCD barrier measured 8-12 us/sync (R4/R5/R6).
__global__ void matvec_div_kernel(const float* __restrict__ M, const float* __restrict__ x,
                                  float* __restrict__ y) {
  const int r = blockIdx.x;          // 0..512
  const int lane = threadIdx.x;      // one wave
  const float* row = M + (size_t)r * 513;
  float s = 0.f;
  for (int i = lane; i < 513; i += 64) s += row[i] * x[i];
  #pragma unroll
  for (int off = 32; off; off >>= 1) s += __shfl_xor(s, off);
  if (lane == 0) {
    const float mu = (r == KPT) ? 0.5f : (1.0f / 1024.0f);
    y[r] = mu / s;
  }
}

__global__ void probs_kernel(const float* __restrict__ K, const float* __restrict__ a,
                             const float* __restrict__ b, float* __restrict__ out) {
  int t = blockIdx.x * blockDim.x + threadIdx.x;
  int t4 = t * 4;
  if (t4 + 3 < 513 * 513) {
    float4 kv = *(const float4*)&K[t4];
    float o[4];
    #pragma unroll
    for (int e = 0; e < 4; ++e) {
      int idx = t4 + e;
      int k = idx / 513;
      int l = idx - k * 513;
      float v = (e == 0) ? kv.x : (e == 1) ? kv.y : (e == 2) ? kv.z : kv.w;
      o[e] = v * (a[k] * 1024.f) * b[l];
    }
    *(float4*)&out[t4] = make_float4(o[0], o[1], o[2], o[3]);
  } else {
    for (int idx = t4; idx < 513 * 513; ++idx) {
      int k = idx / 513;
      int l = idx - k * 513;
      out[idx] = K[idx] * (a[k] * 1024.f) * b[l];
    }
  }
}

// ---------------------------------------------------------------- launch
extern "C" void kernel_launch(void* const* d_in, const int* in_sizes, int n_in,
                              void* d_out, int out_size, void* d_ws, size_t ws_size,
                              hipStream_t stream) {
  const float* img1 = (const float*)d_in[0];
  const float* img2 = (const float*)d_in[1];
  float* out = (float*)d_out;

  char* p = (char*)d_ws;
  auto alloc = [&](size_t bytes) { char* r = p; p += (bytes + 255) & ~(size_t)255; return r; };
  int*   counts   = (int*)alloc(2 * 4);
  float* sel_val  = (float*)alloc(2 * KPT * 4);
  int*   sel_idx  = (int*)alloc(2 * KPT * 4);
  float* aa       = (float*)alloc(513 * 4);
  float* bb       = (float*)alloc(513 * 4);
  float* a2       = (float*)alloc(2 * KPT * 4);
  float* smooth   = (float*)alloc((size_t)2 * HW * 4);
  float* cand_val = (float*)alloc((size_t)2 * CAP * 4);
  int*   cand_idx = (int*)alloc((size_t)2 * CAP * 4);
  int*   rank_arr = (int*)alloc((size_t)2 * CAP * 4);
  float* desc     = (float*)alloc((size_t)2 * KPT * DESC * 4);
  float* K        = (float*)alloc((size_t)513 * 513 * 4);
  float* Kt       = (float*)alloc((size_t)513 * 513 * 4);

  init_misc_kernel<<<64, 256, 0, stream>>>(counts, sel_val, sel_idx, aa, bb, rank_arr, K, Kt);
  det_nms_kernel<<<dim3(IMW / FTW, IMH / FTH, 2), 256, 0, stream>>>(img1, img2, smooth,
                                                                    cand_val, cand_idx, counts);
  rank_partial_kernel<<<dim3(CAP / 256, CAP / 256, 2), 256, 0, stream>>>(cand_val, cand_idx, counts, rank_arr);
  scatter_topk_kernel<<<dim3(CAP / 256, 2), 256, 0, stream>>>(cand_val, cand_idx, counts, rank_arr, sel_val, sel_idx);
  kp_desc_kernel<<<1024, 64, 0, stream>>>(sel_val, sel_idx, smooth, desc, a2, out);
  similarity_tiled_kernel<<<dim3(32, 16), 128, 0, stream>>>(desc, a2, K, Kt);
  for (int it = 0; it < 20; ++it) {
    matvec_div_kernel<<<513, 64, 0, stream>>>(K, bb, aa);   // a = mu / (K b)
    matvec_div_kernel<<<513, 64, 0, stream>>>(Kt, aa, bb);  // b = nu / (K^T a)
  }
  probs_kernel<<<(65793 + 255) / 256, 256, 0, stream>>>(K, aa, bb, out + 2048);
}